// Round 1
// baseline (1862.868 us; speedup 1.0000x reference)
//
#include <hip/hip_runtime.h>

#define BB 16
#define NN 4096
#define SS 1024
#define KNB 32

// exact f32 squared distance, left-to-right, no fma contraction (matches numpy)
__device__ __forceinline__ float sqd3(float dx, float dy, float dz) {
    return __fadd_rn(__fadd_rn(__fmul_rn(dx, dx), __fmul_rn(dy, dy)), __fmul_rn(dz, dz));
}

__device__ __forceinline__ float rlane(float v, int l) {
    return __int_as_float(__builtin_amdgcn_readlane(__float_as_int(v), l));
}

// ---------------- Kernel 1: FPS (one block per batch) ----------------
__global__ __launch_bounds__(512) void fps_kernel(const float* __restrict__ xyz,
                                                  float* __restrict__ out_newxyz) {
    __shared__ float4 pts[NN];
    __shared__ float pval[8];
    __shared__ int   pidx[8];
    __shared__ int   s_far;
    const int b = blockIdx.x;
    const int t = threadIdx.x;
    const float* xb = xyz + (size_t)b * (NN * 3);
    for (int n = t; n < NN; n += 512) {
        pts[n] = make_float4(xb[n * 3 + 0], xb[n * 3 + 1], xb[n * 3 + 2], 0.f);
    }
    __syncthreads();
    float px[8], py[8], pz[8], dist[8];
#pragma unroll
    for (int j = 0; j < 8; ++j) {
        float4 p = pts[t + 512 * j];
        px[j] = p.x; py[j] = p.y; pz[j] = p.z;
        dist[j] = 1e10f;
    }
    int far = 0;
    for (int it = 0; it < SS; ++it) {
        if (t == 0) {
            float4 c = pts[far];
            size_t o = ((size_t)b * SS + it) * 3;
            out_newxyz[o + 0] = c.x;
            out_newxyz[o + 1] = c.y;
            out_newxyz[o + 2] = c.z;
        }
        if (it == SS - 1) break;
        float4 c = pts[far];
        float bv = -1.f;
        int bn = 0;
#pragma unroll
        for (int j = 0; j < 8; ++j) {
            float d = sqd3(px[j] - c.x, py[j] - c.y, pz[j] - c.z);
            float dj = fminf(dist[j], d);
            dist[j] = dj;
            bool g = dj > bv;             // strict > keeps earliest index on ties
            bv = g ? dj : bv;
            bn = g ? (t + 512 * j) : bn;
        }
        // wave butterfly argmax, first-index tie-break
#pragma unroll
        for (int off = 32; off >= 1; off >>= 1) {
            float ov = __shfl_xor(bv, off, 64);
            int   on = __shfl_xor(bn, off, 64);
            bool take = (ov > bv) || (ov == bv && on < bn);
            bv = take ? ov : bv;
            bn = take ? on : bn;
        }
        if ((t & 63) == 0) { pval[t >> 6] = bv; pidx[t >> 6] = bn; }
        __syncthreads();
        if (t == 0) {
            float fv = pval[0]; int fn = pidx[0];
#pragma unroll
            for (int w = 1; w < 8; ++w) {
                bool take = (pval[w] > fv) || (pval[w] == fv && pidx[w] < fn);
                fv = take ? pval[w] : fv;
                fn = take ? pidx[w] : fn;
            }
            s_far = fn;
        }
        __syncthreads();
        far = s_far;
    }
}

// ---------------- Kernel 2: P1[n] = xyz[n]*W0_xyz + points[n]*W0_pts + b0 ----------------
__global__ __launch_bounds__(256) void p1_kernel(const float* __restrict__ xyz,
                                                 const float* __restrict__ points,
                                                 const float* __restrict__ W0,
                                                 const float* __restrict__ b0,
                                                 float* __restrict__ P1) {
    __shared__ float w0s[67 * 64];
    const int t = threadIdx.x;
    for (int i = t; i < 67 * 64; i += 256) w0s[i] = W0[i];
    __syncthreads();
    const int lane = t & 63;
    const int wv = t >> 6;
    const float bias = b0[lane];
    const int base = blockIdx.x * 256 + wv * 64;
    for (int pi = 0; pi < 64; ++pi) {
        const int n = base + pi;  // 0 .. B*N-1
        const float* xp = xyz + (size_t)n * 3;
        const float* pp = points + (size_t)n * 64;
        float acc = bias;
        acc = fmaf(xp[0], w0s[0 * 64 + lane], acc);
        acc = fmaf(xp[1], w0s[1 * 64 + lane], acc);
        acc = fmaf(xp[2], w0s[2 * 64 + lane], acc);
#pragma unroll 8
        for (int c = 0; c < 64; ++c) acc = fmaf(pp[c], w0s[(3 + c) * 64 + lane], acc);
        P1[(size_t)n * 64 + lane] = acc;
    }
}

// ---------------- Kernel 3: ball query + MLP(l2,l3) + max, one block per (b,s) ----------------
__global__ __launch_bounds__(256) void k3_kernel(const float* __restrict__ xyz,
                                                 const float* __restrict__ P1,
                                                 const float* __restrict__ W0,
                                                 const float* __restrict__ W1,
                                                 const float* __restrict__ b1,
                                                 const float* __restrict__ W2,
                                                 const float* __restrict__ b2,
                                                 float* __restrict__ d_out) {
    const int t = threadIdx.x;
    const int lane = t & 63;
    const int wv = t >> 6;
    const int b = blockIdx.x >> 10;

    __shared__ int   ids[KNB];
    __shared__ int   s_cnt;
    __shared__ float part[4][128];

    float* out_newxyz = d_out;                                   // B*S*3
    float* out_points = d_out + (size_t)BB * SS * 3;             // B*S*128
    float* out_idx    = d_out + (size_t)BB * SS * 3 + (size_t)BB * SS * 128;  // B*S*32

    const size_t q = (size_t)blockIdx.x;  // b*S + s
    const float nx = out_newxyz[q * 3 + 0];
    const float ny = out_newxyz[q * 3 + 1];
    const float nz = out_newxyz[q * 3 + 2];

    // per-channel query projection (layer1 factorization)
    const float qv = nx * W0[lane] + ny * W0[64 + lane] + nz * W0[128 + lane];

    // preload W1 column into registers (coalesced 256B per row)
    float w1col[64];
#pragma unroll
    for (int i = 0; i < 64; ++i) w1col[i] = W1[i * 64 + lane];
    const float b1v = b1[lane];

    // ---- ball query: wave 0 scans chunks of 64 in index order ----
    if (wv == 0) {
        const float* xb = xyz + (size_t)b * (NN * 3);
        const float R2 = 0.04f;  // float(0.2*0.2)
        int total = 0;
        for (int c0 = 0; c0 < NN; c0 += 64) {
            const float* xp = xb + (size_t)(c0 + lane) * 3;
            float d = sqd3(xp[0] - nx, xp[1] - ny, xp[2] - nz);
            bool in = (d <= R2);
            unsigned long long m = __ballot(in);
            int before = __popcll(m & ((1ull << lane) - 1ull));
            int pos = total + before;
            if (in && pos < KNB) ids[pos] = c0 + lane;
            total += __popcll(m);
            if (total >= KNB) break;
        }
        if (lane == 0) s_cnt = (total < KNB) ? total : KNB;
    }
    __syncthreads();
    const int cnt = s_cnt;
    if (t >= cnt && t < KNB) ids[t] = ids[0];  // pad with first (reference semantics)
    __syncthreads();
    if (t < KNB) out_idx[q * KNB + t] = (float)ids[t];

    // ---- gather + layer1: h1[k][i=lane] = relu(P1[n_k][lane] - qv) ----
    const float* P1b = P1 + (size_t)b * NN * 64;
    float h1reg[8];
#pragma unroll
    for (int kk = 0; kk < 8; ++kk) {
        int n = ids[wv * 8 + kk];
        float v = P1b[(size_t)n * 64 + lane] - qv;
        h1reg[kk] = fmaxf(v, 0.f);
    }

    // ---- layer2: out[k][o=lane] = relu(b1 + sum_i h1[k][i] * W1[i][o]) ----
    float acc[8];
#pragma unroll
    for (int kk = 0; kk < 8; ++kk) acc[kk] = b1v;
#pragma unroll
    for (int i = 0; i < 64; ++i) {
        float w = w1col[i];
#pragma unroll
        for (int kk = 0; kk < 8; ++kk)
            acc[kk] = fmaf(rlane(h1reg[kk], i), w, acc[kk]);
    }
    float h2reg[8];
#pragma unroll
    for (int kk = 0; kk < 8; ++kk) h2reg[kk] = fmaxf(acc[kk], 0.f);

    // ---- layer3 (two o-halves) + max over this wave's 8 k ----
    float outmax[2];
#pragma unroll
    for (int p = 0; p < 2; ++p) {
        float w2col[64];
#pragma unroll
        for (int i = 0; i < 64; ++i) w2col[i] = W2[i * 128 + 64 * p + lane];
        const float b2v = b2[64 * p + lane];
        float acc3[8];
#pragma unroll
        for (int kk = 0; kk < 8; ++kk) acc3[kk] = b2v;
#pragma unroll
        for (int i = 0; i < 64; ++i) {
            float w = w2col[i];
#pragma unroll
            for (int kk = 0; kk < 8; ++kk)
                acc3[kk] = fmaf(rlane(h2reg[kk], i), w, acc3[kk]);
        }
        float m = 0.f;  // relu floor: max(relu(x)) == max(0, max(x))
#pragma unroll
        for (int kk = 0; kk < 8; ++kk) m = fmaxf(m, acc3[kk]);
        outmax[p] = m;
    }
    part[wv][lane] = outmax[0];
    part[wv][64 + lane] = outmax[1];
    __syncthreads();
    if (t < 128) {
        float v = fmaxf(fmaxf(part[0][t], part[1][t]), fmaxf(part[2][t], part[3][t]));
        out_points[q * 128 + t] = v;
    }
}

extern "C" void kernel_launch(void* const* d_in, const int* in_sizes, int n_in,
                              void* d_out, int out_size, void* d_ws, size_t ws_size,
                              hipStream_t stream) {
    const float* xyz    = (const float*)d_in[0];
    const float* points = (const float*)d_in[1];
    const float* W0     = (const float*)d_in[2];
    const float* b0     = (const float*)d_in[3];
    const float* W1     = (const float*)d_in[4];
    const float* b1     = (const float*)d_in[5];
    const float* W2     = (const float*)d_in[6];
    const float* b2     = (const float*)d_in[7];
    float* out = (float*)d_out;
    float* P1  = (float*)d_ws;  // B*N*64 floats = 16.78 MB

    hipLaunchKernelGGL(p1_kernel, dim3(BB * NN / 256), dim3(256), 0, stream,
                       xyz, points, W0, b0, P1);
    hipLaunchKernelGGL(fps_kernel, dim3(BB), dim3(512), 0, stream, xyz, out);
    hipLaunchKernelGGL(k3_kernel, dim3(BB * SS), dim3(256), 0, stream,
                       xyz, P1, W0, W1, b1, W2, b2, out);
}

// Round 2
// 1313.803 us; speedup vs baseline: 1.4179x; 1.4179x over previous
//
#include <hip/hip_runtime.h>

#define BB 16
#define NN 4096
#define SS 1024
#define KNB 32
#define PPT 8     // points per thread in FPS (4096/512)
#define NW 8      // waves per 512-thread block

// exact f32 squared distance, left-to-right, no fma contraction (matches numpy)
__device__ __forceinline__ float sqd3(float dx, float dy, float dz) {
    return __fadd_rn(__fadd_rn(__fmul_rn(dx, dx), __fmul_rn(dy, dy)), __fmul_rn(dz, dz));
}

__device__ __forceinline__ float rlane(float v, int l) {
    return __int_as_float(__builtin_amdgcn_readlane(__float_as_int(v), l));
}

// ---------------- Kernel 1: fused FPS (blocks 0..15) + P1 precompute (blocks 16..143) ----
// FPS: one block per batch, contiguous point ownership, single-barrier argmax/iter.
// P1[n] = xyz[n]*W0_xyz + points[n]*W0_pts + b0  (layer-1 factorization, point part)
__global__ __launch_bounds__(512) void fused1_kernel(const float* __restrict__ xyz,
                                                     const float* __restrict__ points,
                                                     const float* __restrict__ W0,
                                                     const float* __restrict__ b0,
                                                     float* __restrict__ P1,
                                                     float* __restrict__ out_newxyz) {
    __shared__ union {
        struct {
            float4 pts[NN];
            unsigned long long pairs[2][NW];
        } f;
        float w0s[67 * 64];
    } sm;

    const int t = threadIdx.x;

    if (blockIdx.x < BB) {
        // ---------------- FPS path ----------------
        const int b = blockIdx.x;
        const float* xb = xyz + (size_t)b * (NN * 3);
        float px[PPT], py[PPT], pz[PPT], dist[PPT];
        const float* src = xb + (size_t)t * (PPT * 3);
#pragma unroll
        for (int j = 0; j < PPT; ++j) {
            float x = src[j * 3 + 0], y = src[j * 3 + 1], z = src[j * 3 + 2];
            px[j] = x; py[j] = y; pz[j] = z;
            dist[j] = 1e10f;
            sm.f.pts[t * PPT + j] = make_float4(x, y, z, 0.f);
        }
        __syncthreads();

        int far = 0;
        for (int it = 0; it < SS; ++it) {
            float4 c = sm.f.pts[far];
            if (t == 0) {
                size_t o = ((size_t)b * SS + it) * 3;
                out_newxyz[o + 0] = c.x;
                out_newxyz[o + 1] = c.y;
                out_newxyz[o + 2] = c.z;
            }
            if (it == SS - 1) break;

            // update dists + local argmax (earliest index wins via strict >)
            float bv = -1.f;
            int bn = 0;
#pragma unroll
            for (int j = 0; j < PPT; ++j) {
                float d = sqd3(px[j] - c.x, py[j] - c.y, pz[j] - c.z);
                float dj = fminf(dist[j], d);
                dist[j] = dj;
                bool g = dj > bv;
                bv = g ? dj : bv;
                bn = g ? (t * PPT + j) : bn;
            }
            // wave-wide value-only max
            float vm = bv;
#pragma unroll
            for (int off = 32; off >= 1; off >>= 1)
                vm = fmaxf(vm, __shfl_xor(vm, off, 64));
            // earliest achiever lane == smallest index (contiguous ownership)
            unsigned long long mask = __ballot(bv == vm);
            int sel = __ffsll((unsigned long long)mask) - 1;
            int widx = __shfl(bn, sel, 64);

            const int par = it & 1;
            if ((t & 63) == 0) {
                sm.f.pairs[par][t >> 6] =
                    ((unsigned long long)__float_as_uint(vm) << 32) | (unsigned)(~widx);
            }
            __syncthreads();
            // every thread combines the 8 keys (u64 max = value max, min-index tiebreak)
            unsigned long long best = sm.f.pairs[par][0];
#pragma unroll
            for (int w = 1; w < NW; ++w) {
                unsigned long long v = sm.f.pairs[par][w];
                best = (v > best) ? v : best;
            }
            far = (int)(~(unsigned)best);
        }
    } else {
        // ---------------- P1 path ----------------
        for (int i = t; i < 67 * 64; i += 512) sm.w0s[i] = W0[i];
        __syncthreads();
        const int lane = t & 63;
        const int wv = t >> 6;
        const float bias = b0[lane];
        const int base = (blockIdx.x - BB) * 512 + wv * 64;
        for (int pi = 0; pi < 64; ++pi) {
            const int n = base + pi;  // 0 .. B*N-1
            const float* xp = xyz + (size_t)n * 3;
            const float* pp = points + (size_t)n * 64;
            float acc = bias;
            acc = fmaf(xp[0], sm.w0s[0 * 64 + lane], acc);
            acc = fmaf(xp[1], sm.w0s[1 * 64 + lane], acc);
            acc = fmaf(xp[2], sm.w0s[2 * 64 + lane], acc);
#pragma unroll 8
            for (int c = 0; c < 64; ++c) acc = fmaf(pp[c], sm.w0s[(3 + c) * 64 + lane], acc);
            P1[(size_t)n * 64 + lane] = acc;
        }
    }
}

// ---------------- Kernel 3: ball query + MLP(l2,l3) + max, one block per (b,s) ----------------
__global__ __launch_bounds__(256) void k3_kernel(const float* __restrict__ xyz,
                                                 const float* __restrict__ P1,
                                                 const float* __restrict__ W0,
                                                 const float* __restrict__ W1,
                                                 const float* __restrict__ b1,
                                                 const float* __restrict__ W2,
                                                 const float* __restrict__ b2,
                                                 float* __restrict__ d_out) {
    const int t = threadIdx.x;
    const int lane = t & 63;
    const int wv = t >> 6;
    const int b = blockIdx.x >> 10;

    __shared__ int   ids[KNB];
    __shared__ int   s_cnt;
    __shared__ float part[4][128];

    float* out_newxyz = d_out;                                   // B*S*3
    float* out_points = d_out + (size_t)BB * SS * 3;             // B*S*128
    float* out_idx    = d_out + (size_t)BB * SS * 3 + (size_t)BB * SS * 128;  // B*S*32

    const size_t q = (size_t)blockIdx.x;  // b*S + s
    const float nx = out_newxyz[q * 3 + 0];
    const float ny = out_newxyz[q * 3 + 1];
    const float nz = out_newxyz[q * 3 + 2];

    // per-channel query projection (layer1 factorization)
    const float qv = nx * W0[lane] + ny * W0[64 + lane] + nz * W0[128 + lane];

    // preload W1 column into registers (coalesced 256B per row)
    float w1col[64];
#pragma unroll
    for (int i = 0; i < 64; ++i) w1col[i] = W1[i * 64 + lane];
    const float b1v = b1[lane];

    // ---- ball query: wave 0 scans chunks of 64 in index order ----
    if (wv == 0) {
        const float* xb = xyz + (size_t)b * (NN * 3);
        const float R2 = 0.04f;  // float(0.2*0.2)
        int total = 0;
        for (int c0 = 0; c0 < NN; c0 += 64) {
            const float* xp = xb + (size_t)(c0 + lane) * 3;
            float d = sqd3(xp[0] - nx, xp[1] - ny, xp[2] - nz);
            bool in = (d <= R2);
            unsigned long long m = __ballot(in);
            int before = __popcll(m & ((1ull << lane) - 1ull));
            int pos = total + before;
            if (in && pos < KNB) ids[pos] = c0 + lane;
            total += __popcll(m);
            if (total >= KNB) break;
        }
        if (lane == 0) s_cnt = (total < KNB) ? total : KNB;
    }
    __syncthreads();
    const int cnt = s_cnt;
    if (t >= cnt && t < KNB) ids[t] = ids[0];  // pad with first (reference semantics)
    __syncthreads();
    if (t < KNB) out_idx[q * KNB + t] = (float)ids[t];

    // ---- gather + layer1: h1[k][i=lane] = relu(P1[n_k][lane] - qv) ----
    const float* P1b = P1 + (size_t)b * NN * 64;
    float h1reg[8];
#pragma unroll
    for (int kk = 0; kk < 8; ++kk) {
        int n = ids[wv * 8 + kk];
        float v = P1b[(size_t)n * 64 + lane] - qv;
        h1reg[kk] = fmaxf(v, 0.f);
    }

    // ---- layer2: out[k][o=lane] = relu(b1 + sum_i h1[k][i] * W1[i][o]) ----
    float acc[8];
#pragma unroll
    for (int kk = 0; kk < 8; ++kk) acc[kk] = b1v;
#pragma unroll
    for (int i = 0; i < 64; ++i) {
        float w = w1col[i];
#pragma unroll
        for (int kk = 0; kk < 8; ++kk)
            acc[kk] = fmaf(rlane(h1reg[kk], i), w, acc[kk]);
    }
    float h2reg[8];
#pragma unroll
    for (int kk = 0; kk < 8; ++kk) h2reg[kk] = fmaxf(acc[kk], 0.f);

    // ---- layer3 (two o-halves) + max over this wave's 8 k ----
    float outmax[2];
#pragma unroll
    for (int p = 0; p < 2; ++p) {
        float w2col[64];
#pragma unroll
        for (int i = 0; i < 64; ++i) w2col[i] = W2[i * 128 + 64 * p + lane];
        const float b2v = b2[64 * p + lane];
        float acc3[8];
#pragma unroll
        for (int kk = 0; kk < 8; ++kk) acc3[kk] = b2v;
#pragma unroll
        for (int i = 0; i < 64; ++i) {
            float w = w2col[i];
#pragma unroll
            for (int kk = 0; kk < 8; ++kk)
                acc3[kk] = fmaf(rlane(h2reg[kk], i), w, acc3[kk]);
        }
        float m = 0.f;  // relu floor: max(relu(x)) == max(0, max(x))
#pragma unroll
        for (int kk = 0; kk < 8; ++kk) m = fmaxf(m, acc3[kk]);
        outmax[p] = m;
    }
    part[wv][lane] = outmax[0];
    part[wv][64 + lane] = outmax[1];
    __syncthreads();
    if (t < 128) {
        float v = fmaxf(fmaxf(part[0][t], part[1][t]), fmaxf(part[2][t], part[3][t]));
        out_points[q * 128 + t] = v;
    }
}

extern "C" void kernel_launch(void* const* d_in, const int* in_sizes, int n_in,
                              void* d_out, int out_size, void* d_ws, size_t ws_size,
                              hipStream_t stream) {
    const float* xyz    = (const float*)d_in[0];
    const float* points = (const float*)d_in[1];
    const float* W0     = (const float*)d_in[2];
    const float* b0     = (const float*)d_in[3];
    const float* W1     = (const float*)d_in[4];
    const float* b1     = (const float*)d_in[5];
    const float* W2     = (const float*)d_in[6];
    const float* b2     = (const float*)d_in[7];
    float* out = (float*)d_out;
    float* P1  = (float*)d_ws;  // B*N*64 floats = 16.78 MB

    // blocks 0..15: FPS (one per batch); blocks 16..143: P1 (512 points each)
    hipLaunchKernelGGL(fused1_kernel, dim3(BB + (BB * NN) / 512), dim3(512), 0, stream,
                       xyz, points, W0, b0, P1, out);
    hipLaunchKernelGGL(k3_kernel, dim3(BB * SS), dim3(256), 0, stream,
                       xyz, P1, W0, W1, b1, W2, b2, out);
}

// Round 4
// 773.057 us; speedup vs baseline: 2.4097x; 1.6995x over previous
//
#include <hip/hip_runtime.h>

#define BB 16
#define NN 4096
#define SS 1024
#define KNB 32
#define FPT 16    // points per thread in FPS (4096/256)
#define FNW 4     // waves per 256-thread FPS block

typedef unsigned long long ull;

// exact f32 squared distance, left-to-right, no fma contraction (matches numpy)
__device__ __forceinline__ float sqd3(float dx, float dy, float dz) {
    return __fadd_rn(__fadd_rn(__fmul_rn(dx, dx), __fmul_rn(dy, dy)), __fmul_rn(dz, dz));
}

// one DPP max step on u32 (float bits of non-negative floats: u32 max == float max)
#define DPPMAX(m, ctrl, rm)                                                              \
    {                                                                                    \
        unsigned _t = (unsigned)__builtin_amdgcn_update_dpp((int)(m), (int)(m), (ctrl),  \
                                                            (rm), 0xf, false);           \
        (m) = ((m) > _t) ? (m) : _t;                                                     \
    }

// ---------------- Kernel 1: fused FPS (blocks 0..15) + P1 (blocks 16..271) ----------------
__global__ __launch_bounds__(256) void fused1_kernel(const float* __restrict__ xyz,
                                                     const float* __restrict__ points,
                                                     const float* __restrict__ W0,
                                                     const float* __restrict__ b0,
                                                     float* __restrict__ P1,
                                                     float* __restrict__ out_newxyz) {
    __shared__ union {
        struct {
            float4 pts[NN];            // 64 KB
            ull    keys[2][FNW];       // parity double-buffer
            int    hist[SS];           // selected index per iteration
        } f;
        float w0s[67 * 64];
    } sm;

    const int t = threadIdx.x;

    if (blockIdx.x < BB) {
        // ---------------- FPS: one block per batch, 4 waves, 16 pts/thread ----------------
        const int b = blockIdx.x;
        const int lane = t & 63;
        const float* src = xyz + (size_t)b * (NN * 3) + (size_t)t * (FPT * 3);

        float px[FPT], py[FPT], pz[FPT], dist[FPT];
        {
            float c48[48];
#pragma unroll
            for (int m = 0; m < 12; ++m) {
                float4 v = ((const float4*)src)[m];
                c48[4 * m + 0] = v.x; c48[4 * m + 1] = v.y;
                c48[4 * m + 2] = v.z; c48[4 * m + 3] = v.w;
            }
#pragma unroll
            for (int j = 0; j < FPT; ++j) {
                px[j] = c48[3 * j + 0];
                py[j] = c48[3 * j + 1];
                pz[j] = c48[3 * j + 2];
                dist[j] = 1e10f;
                sm.f.pts[t * FPT + j] = make_float4(px[j], py[j], pz[j], 0.f);
            }
        }
        __syncthreads();

        int far = 0;
        for (int it = 0; it < SS; ++it) {
            if (t == 0) sm.f.hist[it] = far;
            if (it == SS - 1) break;
            float4 c = sm.f.pts[far];

            // update min-dists + per-thread argmax (strict > keeps earliest index)
            float bv = -1.f;
            int bn = 0;
#pragma unroll
            for (int j = 0; j < FPT; ++j) {
                float d = sqd3(px[j] - c.x, py[j] - c.y, pz[j] - c.z);
                float dj = fminf(dist[j], d);
                dist[j] = dj;
                bool g = dj > bv;
                bv = g ? dj : bv;
                bn = g ? (t * FPT + j) : bn;
            }

            // wave64 DPP max reduce (value only) -> lane 63
            unsigned mb = __float_as_uint(bv);
            DPPMAX(mb, 0x111, 0xf);  // row_shr:1
            DPPMAX(mb, 0x112, 0xf);  // row_shr:2
            DPPMAX(mb, 0x114, 0xf);  // row_shr:4
            DPPMAX(mb, 0x118, 0xf);  // row_shr:8
            DPPMAX(mb, 0x142, 0xa);  // row_bcast:15 -> rows 1,3
            DPPMAX(mb, 0x143, 0xc);  // row_bcast:31 -> rows 2,3
            unsigned vmb = (unsigned)__builtin_amdgcn_readlane((int)mb, 63);

            // earliest lane achieving the max == smallest index (contiguous ownership)
            ull ball = __ballot(__float_as_uint(bv) == vmb);
            int sel = __ffsll(ball) - 1;
            int widx = __builtin_amdgcn_readlane(bn, sel);

            const int par = it & 1;
            if (lane == 0) {
                const int wv = t >> 6;
                sm.f.keys[par][wv] = ((ull)vmb << 32) | (unsigned)(~widx);
            }
            __syncthreads();
            // combine 4 wave keys (u64 max = value max, min-index tiebreak)
            const ull* kp = &sm.f.keys[par][0];
            ull k0 = kp[0], k1 = kp[1], k2 = kp[2], k3 = kp[3];
            ull a0 = (k0 > k1) ? k0 : k1;
            ull a1 = (k2 > k3) ? k2 : k3;
            ull best = (a0 > a1) ? a0 : a1;
            far = (int)(~(unsigned)best);
        }
        __syncthreads();
        // write new_xyz from history
#pragma unroll
        for (int r = 0; r < 4; ++r) {
            int it2 = t + 256 * r;
            int fi = sm.f.hist[it2];
            float4 c = sm.f.pts[fi];
            size_t o = ((size_t)b * SS + it2) * 3;
            out_newxyz[o + 0] = c.x;
            out_newxyz[o + 1] = c.y;
            out_newxyz[o + 2] = c.z;
        }
    } else {
        // ---------------- P1 path: 256 points per block ----------------
        for (int i = t; i < 67 * 64; i += 256) sm.w0s[i] = W0[i];
        __syncthreads();
        const int lane = t & 63;
        const int wv = t >> 6;
        const float bias = b0[lane];
        const int base = (blockIdx.x - BB) * 256 + wv * 64;
        for (int pi = 0; pi < 64; ++pi) {
            const int n = base + pi;  // 0 .. B*N-1
            const float* xp = xyz + (size_t)n * 3;
            const float* pp = points + (size_t)n * 64;
            float acc = bias;
            acc = fmaf(xp[0], sm.w0s[0 * 64 + lane], acc);
            acc = fmaf(xp[1], sm.w0s[1 * 64 + lane], acc);
            acc = fmaf(xp[2], sm.w0s[2 * 64 + lane], acc);
#pragma unroll 8
            for (int c = 0; c < 64; ++c) acc = fmaf(pp[c], sm.w0s[(3 + c) * 64 + lane], acc);
            P1[(size_t)n * 64 + lane] = acc;
        }
    }
}

// ---------------- Kernel 3: ball query + MLP(l2,l3) + max, one block per (b,s) ----------------
__global__ __launch_bounds__(256) void k3_kernel(const float* __restrict__ xyz,
                                                 const float* __restrict__ P1,
                                                 const float* __restrict__ W0,
                                                 const float* __restrict__ W1,
                                                 const float* __restrict__ b1,
                                                 const float* __restrict__ W2,
                                                 const float* __restrict__ b2,
                                                 float* __restrict__ d_out) {
    const int t = threadIdx.x;
    const int lane = t & 63;
    const int wv = t >> 6;
    const int b = blockIdx.x >> 10;

    __shared__ int   ids[KNB];
    __shared__ int   s_cnt;
    __shared__ float part[4][128];
    __shared__ float h1s[4][8][64];
    __shared__ float h2s[4][8][64];

    float* out_newxyz = d_out;                                   // B*S*3
    float* out_points = d_out + (size_t)BB * SS * 3;             // B*S*128
    float* out_idx    = d_out + (size_t)BB * SS * 3 + (size_t)BB * SS * 128;  // B*S*32

    const size_t q = (size_t)blockIdx.x;  // b*S + s
    const float nx = out_newxyz[q * 3 + 0];
    const float ny = out_newxyz[q * 3 + 1];
    const float nz = out_newxyz[q * 3 + 2];

    // ---- ball query first (wave 0), so it isn't delayed by weight preloads ----
    if (wv == 0) {
        const float* xb = xyz + (size_t)b * (NN * 3);
        const float R2 = 0.04f;  // float(0.2*0.2)
        const ull ltmask = (1ull << lane) - 1ull;
        int total = 0;
        for (int c0 = 0; c0 < NN && total < KNB; c0 += 128) {
            const float* xp0 = xb + (size_t)(c0 + lane) * 3;
            const float* xp1 = xb + (size_t)(c0 + 64 + lane) * 3;
            float d0 = sqd3(xp0[0] - nx, xp0[1] - ny, xp0[2] - nz);
            float d1 = sqd3(xp1[0] - nx, xp1[1] - ny, xp1[2] - nz);
            bool in0 = (d0 <= R2);
            bool in1 = (d1 <= R2);
            ull m0 = __ballot(in0);
            ull m1 = __ballot(in1);
            int pc0 = __popcll(m0);
            int pos0 = total + __popcll(m0 & ltmask);
            int pos1 = total + pc0 + __popcll(m1 & ltmask);
            if (in0 && pos0 < KNB) ids[pos0] = c0 + lane;
            if (in1 && pos1 < KNB) ids[pos1] = c0 + 64 + lane;
            total += pc0 + __popcll(m1);
        }
        if (lane == 0) s_cnt = (total < KNB) ? total : KNB;
    }

    // per-channel query projection (layer1 factorization)
    const float qv = nx * W0[lane] + ny * W0[64 + lane] + nz * W0[128 + lane];

    // preload W1 column into registers (coalesced 256B per row)
    float w1col[64];
#pragma unroll
    for (int i = 0; i < 64; ++i) w1col[i] = W1[i * 64 + lane];
    const float b1v = b1[lane];

    __syncthreads();
    const int cnt = s_cnt;
    if (t >= cnt && t < KNB) ids[t] = ids[0];  // pad with first (reference semantics)
    __syncthreads();
    if (t < KNB) out_idx[q * KNB + t] = (float)ids[t];

    // ---- gather + layer1: h1[k][i=lane] = relu(P1[n_k][lane] - qv) ----
    const float* P1b = P1 + (size_t)b * NN * 64;
#pragma unroll
    for (int kk = 0; kk < 8; ++kk) {
        int n = ids[wv * 8 + kk];
        float v = P1b[(size_t)n * 64 + lane] - qv;
        h1s[wv][kk][lane] = fmaxf(v, 0.f);
    }

    // ---- layer2: acc[k][o=lane] = b1 + sum_i h1[k][i] * W1[i][o] ----
    // h1 broadcast via uniform-address ds_read_b128 (4 channels per read)
    float acc[8];
#pragma unroll
    for (int kk = 0; kk < 8; ++kk) acc[kk] = b1v;
#pragma unroll
    for (int qd = 0; qd < 16; ++qd) {
#pragma unroll
        for (int kk = 0; kk < 8; ++kk) {
            float4 h4 = *(const float4*)&h1s[wv][kk][4 * qd];
            acc[kk] = fmaf(h4.x, w1col[4 * qd + 0], acc[kk]);
            acc[kk] = fmaf(h4.y, w1col[4 * qd + 1], acc[kk]);
            acc[kk] = fmaf(h4.z, w1col[4 * qd + 2], acc[kk]);
            acc[kk] = fmaf(h4.w, w1col[4 * qd + 3], acc[kk]);
        }
    }
#pragma unroll
    for (int kk = 0; kk < 8; ++kk) h2s[wv][kk][lane] = fmaxf(acc[kk], 0.f);

    // ---- layer3 (two o-halves) + max over this wave's 8 k ----
    float outmax[2];
#pragma unroll
    for (int p = 0; p < 2; ++p) {
        float w2col[64];
#pragma unroll
        for (int i = 0; i < 64; ++i) w2col[i] = W2[i * 128 + 64 * p + lane];
        const float b2v = b2[64 * p + lane];
        float acc3[8];
#pragma unroll
        for (int kk = 0; kk < 8; ++kk) acc3[kk] = b2v;
#pragma unroll
        for (int qd = 0; qd < 16; ++qd) {
#pragma unroll
            for (int kk = 0; kk < 8; ++kk) {
                float4 h4 = *(const float4*)&h2s[wv][kk][4 * qd];
                acc3[kk] = fmaf(h4.x, w2col[4 * qd + 0], acc3[kk]);
                acc3[kk] = fmaf(h4.y, w2col[4 * qd + 1], acc3[kk]);
                acc3[kk] = fmaf(h4.z, w2col[4 * qd + 2], acc3[kk]);
                acc3[kk] = fmaf(h4.w, w2col[4 * qd + 3], acc3[kk]);
            }
        }
        float m = 0.f;  // relu floor: max(relu(x)) == max(0, max(x))
#pragma unroll
        for (int kk = 0; kk < 8; ++kk) m = fmaxf(m, acc3[kk]);
        outmax[p] = m;
    }
    part[wv][lane] = outmax[0];
    part[wv][64 + lane] = outmax[1];
    __syncthreads();
    if (t < 128) {
        float v = fmaxf(fmaxf(part[0][t], part[1][t]), fmaxf(part[2][t], part[3][t]));
        out_points[q * 128 + t] = v;
    }
}

extern "C" void kernel_launch(void* const* d_in, const int* in_sizes, int n_in,
                              void* d_out, int out_size, void* d_ws, size_t ws_size,
                              hipStream_t stream) {
    const float* xyz    = (const float*)d_in[0];
    const float* points = (const float*)d_in[1];
    const float* W0     = (const float*)d_in[2];
    const float* b0     = (const float*)d_in[3];
    const float* W1     = (const float*)d_in[4];
    const float* b1     = (const float*)d_in[5];
    const float* W2     = (const float*)d_in[6];
    const float* b2     = (const float*)d_in[7];
    float* out = (float*)d_out;
    float* P1  = (float*)d_ws;  // B*N*64 floats = 16.78 MB

    // blocks 0..15: FPS (one per batch); blocks 16..271: P1 (256 points each)
    hipLaunchKernelGGL(fused1_kernel, dim3(BB + (BB * NN) / 256), dim3(256), 0, stream,
                       xyz, points, W0, b0, P1, out);
    hipLaunchKernelGGL(k3_kernel, dim3(BB * SS), dim3(256), 0, stream,
                       xyz, P1, W0, W1, b1, W2, b2, out);
}